// Round 1
// baseline (3367.729 us; speedup 1.0000x reference)
//
#include <hip/hip_runtime.h>
#include <hip/hip_bf16.h>

#define NT   512
#define CHS  294912      // channel stride = D*H*W = 32*96*96
#define HALF 37748736    // B*C*D*H*W = one output tensor

__device__ __forceinline__ float b2f(unsigned short s){ return __uint_as_float(((unsigned)s)<<16); }
__device__ __forceinline__ float bflo(unsigned u){ return __uint_as_float(u<<16); }
__device__ __forceinline__ float bfhi(unsigned u){ return __uint_as_float(u & 0xffff0000u); }
__device__ __forceinline__ unsigned short f2b(float f){
  unsigned u = __float_as_uint(f);
  u += 0x7fffu + ((u>>16)&1u);          // round-to-nearest-even
  return (unsigned short)(u>>16);
}

// LDS row strides: 66 for 64-wide (bf16, 132B rows -> bank shift 1, conflict-free
// column access), 98 for 96-wide (196B rows -> bank shift 17, conflict-free).
__global__ __launch_bounds__(NT) void scam_fused(
  const float* __restrict__ xl, const float* __restrict__ xr,
  const float* __restrict__ nlw, const float* __restrict__ nlb,
  const float* __restrict__ nrw, const float* __restrict__ nrb,
  const float* __restrict__ l1w, const float* __restrict__ l1b,
  const float* __restrict__ r1w, const float* __restrict__ r1b,
  const float* __restrict__ l2w, const float* __restrict__ l2b,
  const float* __restrict__ r2w, const float* __restrict__ r2b,
  const float* __restrict__ beta, const float* __restrict__ gam,
  float* __restrict__ outl, float* __restrict__ outr)
{
  __shared__ unsigned short T [96*66];   // x staging (raw, then *norm_w for Q phases)
  __shared__ unsigned short Q1[96*66];   // QL -> VR
  __shared__ unsigned short Q2[96*66];   // QR -> weight stage -> VL
  __shared__ unsigned short A [96*98];   // weight stage -> attn -> Prow -> Pcol
  __shared__ float mu[96], rsd[96];      // LN stats; mu reused as 1/rowsum later
  __shared__ float rmax[96], rsum[96], cmax[96], cinv[96];
  __shared__ float k1s[64], k2s[64];     // LN-folding terms

  const int tid = threadIdx.x;
  const int blk = blockIdx.x;            // 0..6143 = b*3072 + d*96 + h
  const int b   = blk / 3072;
  const int dh  = blk - b*3072;
  const int base = b*(64*CHS) + dh*96;   // element (c,w) at base + c*CHS + w

  auto stage = [&](const float* __restrict__ src){
    for (int i = tid; i < 6144; i += NT){
      int c = i / 96, w = i - c*96;                 // consecutive tid -> consecutive w (coalesced)
      T[w*66 + c] = f2b(src[base + c*CHS + w]);
    }
  };

  auto stats = [&](){
    if (tid < 96){
      const unsigned short* tr = &T[tid*66];
      float s = 0.f, ss = 0.f;
      #pragma unroll
      for (int c = 0; c < 64; c++){ float v = b2f(tr[c]); s += v; ss = fmaf(v, v, ss); }
      float m   = s * 0.015625f;
      float var = ss * 0.015625f - m*m;
      mu[tid]  = m;
      rsd[tid] = rsqrtf(var + 1e-5f);
    }
  };

  // scale T by norm_w, stage proj weights (bf16) into wdst, compute LN-fold terms
  auto prep = [&](const float* __restrict__ nw, const float* __restrict__ nb,
                  const float* __restrict__ Wm, const float* __restrict__ bias,
                  unsigned short* wdst){
    for (int i = tid; i < 6144; i += NT){
      int c = i / 96, w = i - c*96;
      T[w*66 + c] = f2b(b2f(T[w*66 + c]) * nw[c]);
    }
    for (int i = tid; i < 4096; i += NT){
      int o = i >> 6, c = i & 63;
      wdst[o*66 + c] = f2b(Wm[i]);
    }
    if (tid < 64){
      float a = 0.f, bz = 0.f;
      #pragma unroll
      for (int c = 0; c < 64; c++){
        float wv = Wm[tid*64 + c];
        a  = fmaf(nw[c], wv, a);
        bz = fmaf(nb[c], wv, bz);
      }
      k1s[tid] = a;
      k2s[tid] = bz + bias[tid];
    }
  };

  // Q[w][o] = oscale * ( rs*sum_c(T'*W) - rs*mu*k1[o] + k2[o] )
  auto projLN = [&](const unsigned short* wsrc, unsigned short* dst, float oscale){
    for (int i = tid; i < 6144; i += NT){
      int o = i / 96, w = i - o*96;
      const unsigned* ta = (const unsigned*)&T[w*66];
      const unsigned* wa = (const unsigned*)&wsrc[o*66];
      float a0 = 0.f, a1 = 0.f;
      #pragma unroll
      for (int c2 = 0; c2 < 32; c2++){
        unsigned tu = ta[c2], wu = wa[c2];
        a0 = fmaf(bflo(tu), bflo(wu), a0);
        a1 = fmaf(bfhi(tu), bfhi(wu), a1);
      }
      float q = rsd[w]*(a0+a1) - rsd[w]*mu[w]*k1s[o] + k2s[o];
      dst[w*66 + o] = f2b(q * oscale);
    }
  };

  auto projV = [&](const unsigned short* wsrc, unsigned short* dst, const float* __restrict__ bias){
    for (int i = tid; i < 6144; i += NT){
      int o = i / 96, w = i - o*96;
      const unsigned* ta = (const unsigned*)&T[w*66];
      const unsigned* wa = (const unsigned*)&wsrc[o*66];
      float a0 = 0.f, a1 = 0.f;
      #pragma unroll
      for (int c2 = 0; c2 < 32; c2++){
        unsigned tu = ta[c2], wu = wa[c2];
        a0 = fmaf(bflo(tu), bflo(wu), a0);
        a1 = fmaf(bfhi(tu), bfhi(wu), a1);
      }
      dst[w*66 + o] = f2b(a0 + a1 + bias[o]);
    }
  };

  // ---- left Q (0.125 = C^-0.5 folded into QL) ----
  stage(xl);                       __syncthreads();
  stats();                         __syncthreads();
  prep(nlw, nlb, l1w, l1b, A);     __syncthreads();
  projLN(A, Q1, 0.125f);           __syncthreads();
  // ---- right Q ----
  stage(xr);                       __syncthreads();
  stats();                         __syncthreads();
  prep(nrw, nrb, r1w, r1b, A);     __syncthreads();
  projLN(A, Q2, 1.0f);             __syncthreads();

  // ---- attn = (0.125*QL) . QR^T ----
  for (int i = tid; i < 9216; i += NT){
    int w = i / 96, v = i - w*96;
    const unsigned* qa = (const unsigned*)&Q1[w*66];
    const unsigned* qb = (const unsigned*)&Q2[v*66];
    float a0 = 0.f, a1 = 0.f;
    #pragma unroll
    for (int c2 = 0; c2 < 32; c2++){
      unsigned x = qa[c2], y = qb[c2];
      a0 = fmaf(bflo(x), bflo(y), a0);
      a1 = fmaf(bfhi(x), bfhi(y), a1);
    }
    A[w*98 + v] = f2b(a0 + a1);
  }
  __syncthreads();

  // ---- softmax stats: rows (tid<96) and cols (96<=tid<192) in parallel ----
  if (tid < 96){
    const unsigned short* ar = &A[tid*98];
    float m = -3.0e38f;
    #pragma unroll
    for (int v = 0; v < 96; v++) m = fmaxf(m, b2f(ar[v]));
    float s = 0.f;
    for (int v = 0; v < 96; v++) s += __expf(b2f(ar[v]) - m);
    rmax[tid] = m; rsum[tid] = s; mu[tid] = 1.0f / s;   // mu := 1/rowsum
  } else if (tid < 192){
    int v = tid - 96;
    float m = -3.0e38f;
    for (int w = 0; w < 96; w++) m = fmaxf(m, b2f(A[w*98 + v]));
    float s = 0.f;
    for (int w = 0; w < 96; w++) s += __expf(b2f(A[w*98 + v]) - m);
    cmax[v] = m; cinv[v] = 1.0f / s;
  }
  __syncthreads();

  // ---- Prow in place; restage raw xr into T; stage r2_w into Q2 ----
  for (int i = tid; i < 9216; i += NT){
    int w = i / 96, v = i - w*96;
    float a = b2f(A[w*98 + v]);
    A[w*98 + v] = f2b(__expf(a - rmax[w]) * mu[w]);
  }
  for (int i = tid; i < 6144; i += NT){
    int c = i / 96, w = i - c*96;
    T[w*66 + c] = f2b(xr[base + c*CHS + w]);
  }
  for (int i = tid; i < 4096; i += NT){
    int o = i >> 6, c = i & 63;
    Q2[o*66 + c] = f2b(r2w[i]);
  }
  __syncthreads();

  projV(Q2, Q1, r2b);              __syncthreads();   // VR -> Q1

  // ---- F_r2l = Prow . VR ; out_l = x_l + F*beta ----
  for (int i = tid; i < 6144; i += NT){
    int c = i / 96, w = i - c*96;                      // consecutive tid -> consecutive w (coalesced out)
    const unsigned* pu = (const unsigned*)&A[w*98];
    float a0 = 0.f, a1 = 0.f;
    #pragma unroll
    for (int v2 = 0; v2 < 48; v2++){
      unsigned pv = pu[v2];
      a0 = fmaf(bflo(pv), b2f(Q1[(2*v2)*66 + c]),   a0);
      a1 = fmaf(bfhi(pv), b2f(Q1[(2*v2+1)*66 + c]), a1);
    }
    int g = base + c*CHS + w;
    outl[g] = xl[g] + (a0 + a1) * beta[c];
  }
  __syncthreads();

  // ---- Pcol in place (from Prow); restage raw xl; stage l2_w into Q1 ----
  for (int i = tid; i < 9216; i += NT){
    int w = i / 96, v = i - w*96;
    float p = b2f(A[w*98 + v]);
    A[w*98 + v] = f2b(p * rsum[w] * __expf(rmax[w] - cmax[v]) * cinv[v]);
  }
  for (int i = tid; i < 6144; i += NT){
    int c = i / 96, w = i - c*96;
    T[w*66 + c] = f2b(xl[base + c*CHS + w]);
  }
  for (int i = tid; i < 4096; i += NT){
    int o = i >> 6, c = i & 63;
    Q1[o*66 + c] = f2b(l2w[i]);
  }
  __syncthreads();

  projV(Q1, Q2, l2b);              __syncthreads();   // VL -> Q2

  // ---- F_l2r[v][c] = sum_w Pcol[w][v]*VL[w][c] ; out_r = x_r + F*gamma ----
  for (int i = tid; i < 6144; i += NT){
    int c = i / 96, v = i - c*96;
    float a0 = 0.f, a1 = 0.f;
    #pragma unroll
    for (int w2 = 0; w2 < 48; w2++){
      a0 = fmaf(b2f(A[(2*w2)*98 + v]),   b2f(Q2[(2*w2)*66 + c]),   a0);
      a1 = fmaf(b2f(A[(2*w2+1)*98 + v]), b2f(Q2[(2*w2+1)*66 + c]), a1);
    }
    int g = base + c*CHS + v;
    outr[g] = xr[g] + (a0 + a1) * gam[c];
  }
}

extern "C" void kernel_launch(void* const* d_in, const int* in_sizes, int n_in,
                              void* d_out, int out_size, void* d_ws, size_t ws_size,
                              hipStream_t stream)
{
  const float* xl  = (const float*)d_in[0];
  const float* xr  = (const float*)d_in[1];
  const float* nlw = (const float*)d_in[2];
  const float* nlb = (const float*)d_in[3];
  const float* nrw = (const float*)d_in[4];
  const float* nrb = (const float*)d_in[5];
  const float* l1w = (const float*)d_in[6];
  const float* l1b = (const float*)d_in[7];
  const float* r1w = (const float*)d_in[8];
  const float* r1b = (const float*)d_in[9];
  const float* l2w = (const float*)d_in[10];
  const float* l2b = (const float*)d_in[11];
  const float* r2w = (const float*)d_in[12];
  const float* r2b = (const float*)d_in[13];
  const float* beta= (const float*)d_in[14];
  const float* gam = (const float*)d_in[15];
  float* outl = (float*)d_out;
  float* outr = outl + HALF;

  scam_fused<<<dim3(6144), dim3(NT), 0, stream>>>(
      xl, xr, nlw, nlb, nrw, nrb, l1w, l1b, r1w, r1b,
      l2w, l2b, r2w, r2b, beta, gam, outl, outr);
}